// Round 16
// baseline (207.954 us; speedup 1.0000x reference)
//
#include <hip/hip_runtime.h>
#include <hip/hip_bf16.h>

typedef unsigned short ushort_t;
typedef __attribute__((ext_vector_type(8))) short s16x8;   // 8 bf16 (4 VGPRs)
typedef __attribute__((ext_vector_type(4))) float f32x4;
typedef __attribute__((ext_vector_type(16))) float f32x16;
typedef __attribute__((ext_vector_type(4))) unsigned int u32x4;

#define EMB 768
#define HEADS 12
#define DH 64
#define BATCH 4
#define SEQ 2048
#define MTOK (BATCH*SEQ)     // 8192
#define NQKV (3*EMB)         // 2304
#define NBH (BATCH*HEADS)    // 48
#define LOG2E 1.44269504088896f

__device__ __forceinline__ ushort_t f2bf(float f) {
  unsigned u = __float_as_uint(f);
  u += 0x7fffu + ((u >> 16) & 1u);   // RNE; inputs have no NaN/Inf
  return (ushort_t)(u >> 16);
}
__device__ __forceinline__ unsigned pk2bf(float a, float b) {
  return (unsigned)f2bf(a) | ((unsigned)f2bf(b) << 16);
}
__device__ __forceinline__ unsigned cvtpk(float lo, float hi_) {
  unsigned d;
  asm("v_cvt_pk_bf16_f32 %0, %1, %2" : "=v"(d) : "v"(lo), "v"(hi_));
  return d;
}

__device__ __forceinline__ void gload_lds16(const void* g, void* l) {
  __builtin_amdgcn_global_load_lds(
      (const __attribute__((address_space(1))) unsigned*)g,
      (__attribute__((address_space(3))) unsigned*)l, 16, 0, 0);
}

// ---------------- fp32 -> bf16 convert (vectorized float4 -> 4x bf16) ----------------
__global__ void cvt_bf16(const float* __restrict__ in, ushort_t* __restrict__ out, int n4) {
  int i = blockIdx.x * blockDim.x + threadIdx.x;
  if (i >= n4) return;
  const float4 v = reinterpret_cast<const float4*>(in)[i];
  reinterpret_cast<uint2*>(out)[i] = make_uint2(pk2bf(v.x, v.y), pk2bf(v.z, v.w));
}

// ---- qkv_w convert + ROW PERMUTE: out'[which*768 + h*64 + d] = w[h*192 + 3d + which].
__global__ void cvt_wqkv(const float* __restrict__ w, const float* __restrict__ bias,
                         ushort_t* __restrict__ out, float* __restrict__ bias_p, int n4) {
  int i = blockIdx.x * blockDim.x + threadIdx.x;
  if (i >= n4) return;
  const int srcrow = i / 192;          // EMB/4 = 192 float4 per row
  const int c4 = i - srcrow * 192;
  const int h = srcrow / 192;
  const int rem = srcrow - h * 192;
  const int d = rem / 3;
  const int which = rem - d * 3;
  const int dstrow = which * 768 + h * 64 + d;
  const float4 v = reinterpret_cast<const float4*>(w)[i];
  reinterpret_cast<uint2*>(out)[dstrow * 192 + c4] =
      make_uint2(pk2bf(v.x, v.y), pk2bf(v.z, v.w));
  if (c4 == 0) bias_p[dstrow] = bias[srcrow];
}

// ---------------- GEMM: C[M,N] = A[M,K] @ BT[N,K]^T + bias ----------------
// BK=64, 12 steps; 2-buffer ping-pong with counted vmcnt(8) (r13, neutral-verified).
#define TM 128
#define TN 128
#define BKG 64
#define GSTEPS 12   // K/BKG = 768/64

template<int MODE>
__global__ __launch_bounds__(256, 2) void gemm_bt(
    const ushort_t* __restrict__ A, const ushort_t* __restrict__ BT,
    const float* __restrict__ bias, float* __restrict__ Cf,
    ushort_t* __restrict__ Qd, ushort_t* __restrict__ Kd, ushort_t* __restrict__ Vt,
    int M, int N, int K)
{
  __shared__ alignas(16) ushort_t As[2][TM*BKG];   // 16KB per buffer, XOR-swizzled
  __shared__ alignas(16) ushort_t Bs[2][TN*BKG];
  const int t = threadIdx.x;
  const int w = t >> 6, l = t & 63, g = l >> 4, r = l & 15;
  const int wr = w >> 1, wc = w & 1;                 // 2x2 wave grid, 64x64 per wave
  // XCD-chunked swizzle (grid sizes are multiples of 8)
  int lin = blockIdx.y * gridDim.x + blockIdx.x;
  const int cpx = (gridDim.x * gridDim.y) >> 3;
  lin = (lin & 7) * cpx + (lin >> 3);
  const int m0 = (lin / gridDim.x) * TM, n0 = (lin - (lin / gridDim.x) * gridDim.x) * TN;

  f32x4 acc[4][4] = {};

#define GSTAGE(bufc, st)                                                           \
  {                                                                                \
    const int kt = (st) * BKG;                                                     \
    _Pragma("unroll")                                                              \
    for (int p = 0; p < 4; ++p) {                                                  \
      const int off = (t + p*256) * 16;              /* byte in 16KB tile */       \
      const int row = off >> 7;                      /* 128B per row */            \
      const int scb = (off & 127) ^ ((row & 7) << 4);                              \
      gload_lds16(A  + (size_t)(m0+row)*K + kt + (scb>>1), (char*)&As[bufc][0] + off); \
      gload_lds16(BT + (size_t)(n0+row)*K + kt + (scb>>1), (char*)&Bs[bufc][0] + off); \
    }                                                                              \
  }

#define GCOMP(bufc)                                                                \
  {                                                                                \
    s16x8 fa[4][2], fb[4][2];                                                      \
    _Pragma("unroll")                                                              \
    for (int mi = 0; mi < 4; ++mi)                                                 \
      _Pragma("unroll")                                                            \
      for (int kk = 0; kk < 2; ++kk) {                                             \
        const int ra = wr*64 + mi*16 + r;                                          \
        fa[mi][kk] = *(const s16x8*)((const char*)&As[bufc][0] + ra*128 +          \
                                     ((g*16 + kk*64) ^ ((ra&7)<<4)));              \
        const int rb = wc*64 + mi*16 + r;                                          \
        fb[mi][kk] = *(const s16x8*)((const char*)&Bs[bufc][0] + rb*128 +          \
                                     ((g*16 + kk*64) ^ ((rb&7)<<4)));              \
      }                                                                            \
    __builtin_amdgcn_s_setprio(1);                                                 \
    _Pragma("unroll")                                                              \
    for (int mi = 0; mi < 4; ++mi)                                                 \
      _Pragma("unroll")                                                            \
      for (int ni = 0; ni < 4; ++ni) {                                             \
        acc[mi][ni] = __builtin_amdgcn_mfma_f32_16x16x32_bf16(                     \
            fa[mi][0], fb[ni][0], acc[mi][ni], 0, 0, 0);                           \
        acc[mi][ni] = __builtin_amdgcn_mfma_f32_16x16x32_bf16(                     \
            fa[mi][1], fb[ni][1], acc[mi][ni], 0, 0, 0);                           \
      }                                                                            \
    __builtin_amdgcn_s_setprio(0);                                                 \
  }

#define GITER(cur, st)                                                             \
  {                                                                                \
    asm volatile("s_barrier" ::: "memory");                                        \
    { const int s1 = (st) + 1 < GSTEPS ? (st) + 1 : GSTEPS - 1;                    \
      GSTAGE((cur) ^ 1, s1); }                                                     \
    asm volatile("s_waitcnt vmcnt(8)" ::: "memory");                               \
    asm volatile("s_barrier" ::: "memory");                                        \
    GCOMP(cur);                                                                    \
  }

  GSTAGE(0, 0);
#pragma unroll
  for (int s = 0; s < GSTEPS; ++s) GITER(s & 1, s);
#undef GITER
#undef GCOMP
#undef GSTAGE

  // epilogue: C/D layout col = lane&15, row = (lane>>4)*4 + reg
#pragma unroll
  for (int ni = 0; ni < 4; ++ni) {
    const int col = n0 + wc*64 + ni*16 + r;
    const float bv = bias[col];                       // MODE 1: permuted bias
    if (MODE == 0) {
#pragma unroll
      for (int mi = 0; mi < 4; ++mi)
#pragma unroll
        for (int q = 0; q < 4; ++q) {
          const int rowg = m0 + wr*64 + mi*16 + g*4 + q;
          Cf[(size_t)rowg * N + col] = acc[mi][ni][q] + bv;
        }
    } else {
      const int which = col / 768;
      const int h_ = (col - which * 768) >> 6;
      const int d_ = col & 63;
      if (which == 2) {
#pragma unroll
        for (int mi = 0; mi < 4; ++mi) {
          const int nn0 = m0 + wr*64 + mi*16 + g*4;   // multiple of 4
          const int bb = nn0 >> 11, nl = nn0 & 2047;
          const int np0 = (nl & ~12) | ((nl & 4) << 1) | ((nl & 8) >> 1);
          uint2 u;
          u.x = pk2bf(acc[mi][ni][0] + bv, acc[mi][ni][1] + bv);
          u.y = pk2bf(acc[mi][ni][2] + bv, acc[mi][ni][3] + bv);
          *reinterpret_cast<uint2*>(Vt + ((size_t)(bb*HEADS + h_)*DH + d_)*SEQ + np0) = u;
        }
      } else {
        ushort_t* dst = (which == 0) ? Qd : Kd;
        const float sc = (which == 0) ? LOG2E : 1.0f;
#pragma unroll
        for (int mi = 0; mi < 4; ++mi)
#pragma unroll
          for (int q = 0; q < 4; ++q) {
            const int rowg = m0 + wr*64 + mi*16 + g*4 + q;
            const int bb = rowg >> 11, nn = rowg & 2047;
            dst[((size_t)(bb*HEADS + h_)*SEQ + nn)*DH + d_] =
                f2bf((acc[mi][ni][q] + bv) * sc);
          }
      }
    }
  }
}

// ---------------- flash attention: 64q/wave + split-K + 3-buffer counted vmcnt -------
// 768 blocks = 48 bh x 8 qt(256q) x 2 key-halves; 4 waves x 64q; 3 blocks/CU
// (48KB LDS) = 12 waves/CU. Each ds_read_b128 feeds 2 MFMAs (r6's dual-q KGROUP,
// verified) -> LDS traffic halved vs r9 at SAME TLP. Pipeline = r9's 3-buffer,
// stage 2-ahead, vmcnt(8), never drained to 0. Partials exact under fixed-max=0.
#define NTILH 16

__global__ __launch_bounds__(256, 3) void attn_fwd(
    const ushort_t* __restrict__ Qd, const ushort_t* __restrict__ Kd,
    const ushort_t* __restrict__ Vt, ushort_t* __restrict__ Op0,
    ushort_t* __restrict__ Op1, float* __restrict__ Lp)
{
  __shared__ alignas(16) char L[3][16384];   // per buf: K 8KB (seg*1024+key*16) | V 8KB
  char* Lc = &L[0][0];

  const int t = threadIdx.x;
  const int w = t >> 6, l = t & 63;
  const int c31 = l & 31, hi = l >> 5;
  const int blk = blockIdx.x;
  const int logical = (blk & 7) * 96 + (blk >> 3);   // XCD-chunked
  const int bh = logical >> 4;
  const int rem = logical & 15;
  const int half = rem >> 3;
  const int qt = rem & 7;
  const int q0 = qt * 256 + w * 64;                  // this wave's 64 query rows
  const int tb = half * NTILH;                       // first KV tile of this block

  const ushort_t* Qp = Qd + (size_t)bh * SEQ * DH;
  const ushort_t* Kp = Kd + (size_t)bh * SEQ * DH;
  const ushort_t* Vp = Vt + (size_t)bh * DH * SEQ;

  // Q B-frags, 2 sets (q0..q0+31 and q0+32..q0+63), pre-scaled by log2e
  s16x8 qf0[4], qf1[4];
  {
    const ushort_t* qp0 = Qp + (size_t)(q0 + c31) * DH + hi * 8;
    const ushort_t* qp1 = qp0 + 32 * DH;
#pragma unroll
    for (int c = 0; c < 4; ++c) { qf0[c] = *(const s16x8*)(qp0 + c*16);
                                  qf1[c] = *(const s16x8*)(qp1 + c*16); }
  }

  f32x16 oa00 = {}, oa01 = {};   // q-half 0: d 0..31 / 32..63 (O^T, col q = l&31)
  f32x16 oa10 = {}, oa11 = {};   // q-half 1
  float ps00 = 0.f, ps01 = 0.f, ps10 = 0.f, ps11 = 0.f;

  const int ldsb = hi * 1024 + c31 * 16;             // per-lane ds_read base (byte)
  const ushort_t* ksrc0 = Kp + (size_t)l * DH + w * 16;   // + tile*4096
  const ushort_t* vsrc0 = Vp + (size_t)l * SEQ + w * 16;  // + tile*64
  char* kdst0 = Lc + w * 2048 + l * 16;                   // + buf*16384

#define STAGE(bufc, tile_)                                                         \
  {                                                                                \
    const int tl = (tile_);                                                        \
    const ushort_t* ks = ksrc0 + (size_t)tl * (64 * DH);                           \
    const ushort_t* vs = vsrc0 + tl * 64;                                          \
    char* kd = kdst0 + (bufc) * 16384;                                             \
    gload_lds16(ks,     kd);                                                       \
    gload_lds16(ks + 8, kd + 1024);                                                \
    gload_lds16(vs,     kd + 8192);                                                \
    gload_lds16(vs + 8, kd + 9216);                                                \
  }

  // one 32-key group: 8 ds_read_b128 -> 16 MFMAs (each read feeds 2)
#define KGROUP(bufc, kg)                                                           \
  {                                                                                \
    const char* base = Lc + (bufc) * 16384 + ldsb;                                 \
    s16x8 kf0 = *(const s16x8*)(base + ((kg)*512 + 0*2048));                       \
    s16x8 kf1 = *(const s16x8*)(base + ((kg)*512 + 1*2048));                       \
    s16x8 kf2 = *(const s16x8*)(base + ((kg)*512 + 2*2048));                       \
    s16x8 kf3 = *(const s16x8*)(base + ((kg)*512 + 3*2048));                       \
    s16x8 va00 = *(const s16x8*)(base + (8192 + (kg)*4096 + 0*2048 + 0*512));      \
    s16x8 va01 = *(const s16x8*)(base + (8192 + (kg)*4096 + 1*2048 + 0*512));      \
    s16x8 va10 = *(const s16x8*)(base + (8192 + (kg)*4096 + 0*2048 + 1*512));      \
    s16x8 va11 = *(const s16x8*)(base + (8192 + (kg)*4096 + 1*2048 + 1*512));      \
    __builtin_amdgcn_s_setprio(1);                                                 \
    f32x16 s0 = {}, s1 = {};                                                       \
    s0 = __builtin_amdgcn_mfma_f32_32x32x16_bf16(kf0, qf0[0], s0, 0, 0, 0);        \
    s1 = __builtin_amdgcn_mfma_f32_32x32x16_bf16(kf0, qf1[0], s1, 0, 0, 0);        \
    s0 = __builtin_amdgcn_mfma_f32_32x32x16_bf16(kf1, qf0[1], s0, 0, 0, 0);        \
    s1 = __builtin_amdgcn_mfma_f32_32x32x16_bf16(kf1, qf1[1], s1, 0, 0, 0);        \
    s0 = __builtin_amdgcn_mfma_f32_32x32x16_bf16(kf2, qf0[2], s0, 0, 0, 0);        \
    s1 = __builtin_amdgcn_mfma_f32_32x32x16_bf16(kf2, qf1[2], s1, 0, 0, 0);        \
    s0 = __builtin_amdgcn_mfma_f32_32x32x16_bf16(kf3, qf0[3], s0, 0, 0, 0);        \
    s1 = __builtin_amdgcn_mfma_f32_32x32x16_bf16(kf3, qf1[3], s1, 0, 0, 0);        \
    __builtin_amdgcn_s_setprio(0);                                                 \
    float pe0[16], pe1[16];                                                        \
    _Pragma("unroll")                                                              \
    for (int r2 = 0; r2 < 16; ++r2) {                                              \
      pe0[r2] = __builtin_amdgcn_exp2f(s0[r2]);                                    \
      pe1[r2] = __builtin_amdgcn_exp2f(s1[r2]);                                    \
    }                                                                              \
    ps00 += ((pe0[0]+pe0[1])+(pe0[2]+pe0[3])) + ((pe0[4]+pe0[5])+(pe0[6]+pe0[7])); \
    ps01 += ((pe0[8]+pe0[9])+(pe0[10]+pe0[11]))+((pe0[12]+pe0[13])+(pe0[14]+pe0[15]));\
    ps10 += ((pe1[0]+pe1[1])+(pe1[2]+pe1[3])) + ((pe1[4]+pe1[5])+(pe1[6]+pe1[7])); \
    ps11 += ((pe1[8]+pe1[9])+(pe1[10]+pe1[11]))+((pe1[12]+pe1[13])+(pe1[14]+pe1[15]));\
    u32x4 a0 = { cvtpk(pe0[0],  pe0[1]),  cvtpk(pe0[2],  pe0[3]),                  \
                 cvtpk(pe0[4],  pe0[5]),  cvtpk(pe0[6],  pe0[7]) };                \
    u32x4 a1 = { cvtpk(pe0[8],  pe0[9]),  cvtpk(pe0[10], pe0[11]),                 \
                 cvtpk(pe0[12], pe0[13]), cvtpk(pe0[14], pe0[15]) };               \
    u32x4 b0 = { cvtpk(pe1[0],  pe1[1]),  cvtpk(pe1[2],  pe1[3]),                  \
                 cvtpk(pe1[4],  pe1[5]),  cvtpk(pe1[6],  pe1[7]) };                \
    u32x4 b1 = { cvtpk(pe1[8],  pe1[9]),  cvtpk(pe1[10], pe1[11]),                 \
                 cvtpk(pe1[12], pe1[13]), cvtpk(pe1[14], pe1[15]) };               \
    const s16x8 pf00 = __builtin_bit_cast(s16x8, a0);                              \
    const s16x8 pf01 = __builtin_bit_cast(s16x8, a1);                              \
    const s16x8 pf10 = __builtin_bit_cast(s16x8, b0);                              \
    const s16x8 pf11 = __builtin_bit_cast(s16x8, b1);                              \
    __builtin_amdgcn_s_setprio(1);                                                 \
    oa00 = __builtin_amdgcn_mfma_f32_32x32x16_bf16(va00, pf00, oa00, 0, 0, 0);     \
    oa00 = __builtin_amdgcn_mfma_f32_32x32x16_bf16(va01, pf01, oa00, 0, 0, 0);     \
    oa01 = __builtin_amdgcn_mfma_f32_32x32x16_bf16(va10, pf00, oa01, 0, 0, 0);     \
    oa01 = __builtin_amdgcn_mfma_f32_32x32x16_bf16(va11, pf01, oa01, 0, 0, 0);     \
    oa10 = __builtin_amdgcn_mfma_f32_32x32x16_bf16(va00, pf10, oa10, 0, 0, 0);     \
    oa10 = __builtin_amdgcn_mfma_f32_32x32x16_bf16(va01, pf11, oa10, 0, 0, 0);     \
    oa11 = __builtin_amdgcn_mfma_f32_32x32x16_bf16(va10, pf10, oa11, 0, 0, 0);     \
    oa11 = __builtin_amdgcn_mfma_f32_32x32x16_bf16(va11, pf11, oa11, 0, 0, 0);     \
    __builtin_amdgcn_s_setprio(0);                                                 \
  }

#define ITER(bufcur, bufn2, tt)                                                    \
  {                                                                                \
    asm volatile("s_barrier" ::: "memory");                                        \
    const int nt2 = (tt) + 2 < NTILH ? (tt) + 2 : NTILH - 1;                       \
    STAGE(bufn2, tb + nt2);                                                        \
    asm volatile("s_waitcnt vmcnt(8)" ::: "memory");                               \
    asm volatile("s_barrier" ::: "memory");                                        \
    KGROUP(bufcur, 0);                                                             \
    KGROUP(bufcur, 1);                                                             \
  }

  STAGE(0, tb);
  STAGE(1, tb + 1);
  for (int tt = 0; tt < NTILH - 1; tt += 3) {
    ITER(0, 2, tt);
    ITER(1, 0, tt + 1);
    ITER(2, 1, tt + 2);
  }
  ITER(0, 2, 15);
#undef ITER
#undef KGROUP
#undef STAGE

  // partial row sums: lane l holds 16 of each 32-key group; lane l^32 has the rest
  const float psum0 = ps00 + ps01;
  const float psum1 = ps10 + ps11;
  const float lt0 = psum0 + __shfl_xor(psum0, 32);
  const float lt1 = psum1 + __shfl_xor(psum1, 32);

  // write UNNORMALIZED partial O^T (bf16) to Op[half][bh][q][d]
  ushort_t* Op = half ? Op1 : Op0;
#pragma unroll
  for (int j = 0; j < 2; ++j) {
    ushort_t* op = Op + ((size_t)bh * SEQ + q0 + j*32 + c31) * DH;
#pragma unroll
    for (int f = 0; f < 2; ++f) {
      const f32x16& o = j ? (f ? oa11 : oa10) : (f ? oa01 : oa00);
#pragma unroll
      for (int rq = 0; rq < 4; ++rq) {
        const int dbase = f * 32 + 8 * rq + 4 * hi;    // d = dbase + (reg&3)
        uint2 u;
        u.x = pk2bf(o[rq*4+0], o[rq*4+1]);
        u.y = pk2bf(o[rq*4+2], o[rq*4+3]);
        *reinterpret_cast<uint2*>(op + dbase) = u;
      }
    }
  }
  if (l < 32) {
    Lp[(size_t)half * (NBH * SEQ) + (size_t)bh * SEQ + q0 + c31] = lt0;
    Lp[(size_t)half * (NBH * SEQ) + (size_t)bh * SEQ + q0 + 32 + c31] = lt1;
  }
}

// ---------------- combine partials: Oa = (Op0+Op1) * inv_sqrt768 / (l0+l1) ----------
__global__ void attn_combine(const ushort_t* __restrict__ Op0,
                             const ushort_t* __restrict__ Op1,
                             const float* __restrict__ Lp,
                             ushort_t* __restrict__ Oa) {
  const int i = blockIdx.x * blockDim.x + threadIdx.x;   // NBH*SEQ*8 = 786432
  const int dseg = (i & 7) * 8;
  const int n = (i >> 3) & (SEQ - 1);
  const int bh = i >> 14;
  const int b = bh / HEADS, h = bh - b * HEADS;
  const size_t src = ((size_t)bh * SEQ + n) * DH + dseg;
  const u32x4 a = *reinterpret_cast<const u32x4*>(Op0 + src);
  const u32x4 c = *reinterpret_cast<const u32x4*>(Op1 + src);
  const float lsum = Lp[(size_t)bh * SEQ + n] + Lp[(size_t)NBH * SEQ + (size_t)bh * SEQ + n];
  const float s = 0.036084391824351615f / lsum;   // (1/sqrt(768)) / l
  u32x4 rr;
#pragma unroll
  for (int j = 0; j < 4; ++j) {
    const unsigned x = a[j], y = c[j];
    const float x0 = __uint_as_float(x << 16), x1 = __uint_as_float(x & 0xffff0000u);
    const float y0 = __uint_as_float(y << 16), y1 = __uint_as_float(y & 0xffff0000u);
    rr[j] = pk2bf((x0 + y0) * s, (x1 + y1) * s);
  }
  *reinterpret_cast<u32x4*>(Oa + ((size_t)(b * SEQ + n) * EMB + h * DH + dseg)) = rr;
}

// ---------------- host launch ----------------
extern "C" void kernel_launch(void* const* d_in, const int* in_sizes, int n_in,
                              void* d_out, int out_size, void* d_ws, size_t ws_size,
                              hipStream_t stream) {
  const float* x      = (const float*)d_in[0];
  const float* qkv_w  = (const float*)d_in[1];
  const float* qkv_b  = (const float*)d_in[2];
  const float* proj_w = (const float*)d_in[3];
  const float* proj_b = (const float*)d_in[4];
  float* out = (float*)d_out;

  ushort_t* xb    = (ushort_t*)d_ws;
  ushort_t* wqkv  = xb    + (size_t)MTOK*EMB;
  ushort_t* wproj = wqkv  + (size_t)NQKV*EMB;
  ushort_t* Qd    = wproj + (size_t)EMB*EMB;
  ushort_t* Kd    = Qd    + (size_t)MTOK*EMB;
  ushort_t* Vt    = Kd    + (size_t)MTOK*EMB;
  ushort_t* Oa    = Vt    + (size_t)MTOK*EMB;
  float*    biasp = (float*)(Oa + (size_t)MTOK*EMB);   // 2304 fp32 permuted bias
  ushort_t* Op1   = (ushort_t*)(biasp + 4096);         // 12.6MB bf16 partial (half 1)
  float*    Lp    = (float*)(Op1 + (size_t)MTOK*EMB);  // 2*48*2048 fp32 partial l
  ushort_t* Op0   = xb;                                // reuse: xb dead after gemm1

  {
    int n4 = MTOK*EMB/4;
    cvt_bf16<<<(n4+255)/256, 256, 0, stream>>>(x, xb, n4);
  }
  {
    int n4 = NQKV*EMB/4;
    cvt_wqkv<<<(n4+255)/256, 256, 0, stream>>>(qkv_w, qkv_b, wqkv, biasp, n4);
  }
  {
    int n4 = EMB*EMB/4;
    cvt_bf16<<<(n4+255)/256, 256, 0, stream>>>(proj_w, wproj, n4);
  }

  gemm_bt<1><<<dim3(NQKV/TN, MTOK/TM), 256, 0, stream>>>(
      xb, wqkv, biasp, nullptr, Qd, Kd, Vt, MTOK, NQKV, EMB);

  attn_fwd<<<768, 256, 0, stream>>>(Qd, Kd, Vt, Op0, Op1, Lp);

  attn_combine<<<(NBH*SEQ*8)/256, 256, 0, stream>>>(Op0, Op1, Lp, Oa);

  gemm_bt<0><<<dim3(EMB/TN, MTOK/TM), 256, 0, stream>>>(
      Oa, wproj, proj_b, out, nullptr, nullptr, nullptr, MTOK, EMB, EMB);
}

// Round 17
// 141.692 us; speedup vs baseline: 1.4676x; 1.4676x over previous
//
#include <hip/hip_runtime.h>
#include <hip/hip_bf16.h>

typedef unsigned short ushort_t;
typedef __attribute__((ext_vector_type(8))) short s16x8;   // 8 bf16 (4 VGPRs)
typedef __attribute__((ext_vector_type(4))) float f32x4;
typedef __attribute__((ext_vector_type(16))) float f32x16;
typedef __attribute__((ext_vector_type(4))) unsigned int u32x4;

#define EMB 768
#define HEADS 12
#define DH 64
#define BATCH 4
#define SEQ 2048
#define MTOK (BATCH*SEQ)     // 8192
#define NQKV (3*EMB)         // 2304
#define NBH (BATCH*HEADS)    // 48
#define LOG2E 1.44269504088896f

#define N4X (MTOK*EMB/4)     // 1572864
#define N4W (NQKV*EMB/4)     // 442368
#define N4P (EMB*EMB/4)      // 147456

__device__ __forceinline__ ushort_t f2bf(float f) {
  unsigned u = __float_as_uint(f);
  u += 0x7fffu + ((u >> 16) & 1u);   // RNE; inputs have no NaN/Inf
  return (ushort_t)(u >> 16);
}
__device__ __forceinline__ unsigned pk2bf(float a, float b) {
  return (unsigned)f2bf(a) | ((unsigned)f2bf(b) << 16);
}
__device__ __forceinline__ unsigned cvtpk(float lo, float hi_) {
  unsigned d;
  asm("v_cvt_pk_bf16_f32 %0, %1, %2" : "=v"(d) : "v"(lo), "v"(hi_));
  return d;
}

__device__ __forceinline__ void gload_lds16(const void* g, void* l) {
  __builtin_amdgcn_global_load_lds(
      (const __attribute__((address_space(1))) unsigned*)g,
      (__attribute__((address_space(3))) unsigned*)l, 16, 0, 0);
}

// ---------------- fused fp32->bf16 converts (x | qkv_w row-permute+bias | proj_w) ----
__global__ void cvt_all(const float* __restrict__ x, const float* __restrict__ qkv_w,
                        const float* __restrict__ qkv_b, const float* __restrict__ proj_w,
                        ushort_t* __restrict__ xb, ushort_t* __restrict__ wqkv,
                        float* __restrict__ bias_p, ushort_t* __restrict__ wproj) {
  const int i = blockIdx.x * blockDim.x + threadIdx.x;   // grid = (N4X+N4W+N4P)/256
  if (i < N4X) {
    const float4 v = reinterpret_cast<const float4*>(x)[i];
    reinterpret_cast<uint2*>(xb)[i] = make_uint2(pk2bf(v.x, v.y), pk2bf(v.z, v.w));
  } else if (i < N4X + N4W) {
    const int j = i - N4X;
    const int srcrow = j / 192;          // EMB/4 = 192 float4 per row
    const int c4 = j - srcrow * 192;
    const int h = srcrow / 192;
    const int rem = srcrow - h * 192;
    const int d = rem / 3;
    const int which = rem - d * 3;
    const int dstrow = which * 768 + h * 64 + d;
    const float4 v = reinterpret_cast<const float4*>(qkv_w)[j];
    reinterpret_cast<uint2*>(wqkv)[dstrow * 192 + c4] =
        make_uint2(pk2bf(v.x, v.y), pk2bf(v.z, v.w));
    if (c4 == 0) bias_p[dstrow] = qkv_b[srcrow];
  } else {
    const int j = i - N4X - N4W;
    const float4 v = reinterpret_cast<const float4*>(proj_w)[j];
    reinterpret_cast<uint2*>(wproj)[j] = make_uint2(pk2bf(v.x, v.y), pk2bf(v.z, v.w));
  }
}

// ---------------- GEMM: C[M,N] = A[M,K] @ BT[N,K]^T + bias ----------------
// BK=64, 12 steps; 2-buffer ping-pong with counted vmcnt(8) (r13, verified).
#define TM 128
#define TN 128
#define BKG 64
#define GSTEPS 12   // K/BKG = 768/64

template<int MODE>
__global__ __launch_bounds__(256, 2) void gemm_bt(
    const ushort_t* __restrict__ A, const ushort_t* __restrict__ BT,
    const float* __restrict__ bias, float* __restrict__ Cf,
    ushort_t* __restrict__ Qd, ushort_t* __restrict__ Kd, ushort_t* __restrict__ Vt,
    int M, int N, int K)
{
  __shared__ alignas(16) ushort_t As[2][TM*BKG];   // 16KB per buffer, XOR-swizzled
  __shared__ alignas(16) ushort_t Bs[2][TN*BKG];
  const int t = threadIdx.x;
  const int w = t >> 6, l = t & 63, g = l >> 4, r = l & 15;
  const int wr = w >> 1, wc = w & 1;                 // 2x2 wave grid, 64x64 per wave
  // XCD-chunked swizzle (grid sizes are multiples of 8)
  int lin = blockIdx.y * gridDim.x + blockIdx.x;
  const int cpx = (gridDim.x * gridDim.y) >> 3;
  lin = (lin & 7) * cpx + (lin >> 3);
  const int m0 = (lin / gridDim.x) * TM, n0 = (lin - (lin / gridDim.x) * gridDim.x) * TN;

  f32x4 acc[4][4] = {};

#define GSTAGE(bufc, st)                                                           \
  {                                                                                \
    const int kt = (st) * BKG;                                                     \
    _Pragma("unroll")                                                              \
    for (int p = 0; p < 4; ++p) {                                                  \
      const int off = (t + p*256) * 16;              /* byte in 16KB tile */       \
      const int row = off >> 7;                      /* 128B per row */            \
      const int scb = (off & 127) ^ ((row & 7) << 4);                              \
      gload_lds16(A  + (size_t)(m0+row)*K + kt + (scb>>1), (char*)&As[bufc][0] + off); \
      gload_lds16(BT + (size_t)(n0+row)*K + kt + (scb>>1), (char*)&Bs[bufc][0] + off); \
    }                                                                              \
  }

#define GCOMP(bufc)                                                                \
  {                                                                                \
    s16x8 fa[4][2], fb[4][2];                                                      \
    _Pragma("unroll")                                                              \
    for (int mi = 0; mi < 4; ++mi)                                                 \
      _Pragma("unroll")                                                            \
      for (int kk = 0; kk < 2; ++kk) {                                             \
        const int ra = wr*64 + mi*16 + r;                                          \
        fa[mi][kk] = *(const s16x8*)((const char*)&As[bufc][0] + ra*128 +          \
                                     ((g*16 + kk*64) ^ ((ra&7)<<4)));              \
        const int rb = wc*64 + mi*16 + r;                                          \
        fb[mi][kk] = *(const s16x8*)((const char*)&Bs[bufc][0] + rb*128 +          \
                                     ((g*16 + kk*64) ^ ((rb&7)<<4)));              \
      }                                                                            \
    __builtin_amdgcn_s_setprio(1);                                                 \
    _Pragma("unroll")                                                              \
    for (int mi = 0; mi < 4; ++mi)                                                 \
      _Pragma("unroll")                                                            \
      for (int ni = 0; ni < 4; ++ni) {                                             \
        acc[mi][ni] = __builtin_amdgcn_mfma_f32_16x16x32_bf16(                     \
            fa[mi][0], fb[ni][0], acc[mi][ni], 0, 0, 0);                           \
        acc[mi][ni] = __builtin_amdgcn_mfma_f32_16x16x32_bf16(                     \
            fa[mi][1], fb[ni][1], acc[mi][ni], 0, 0, 0);                           \
      }                                                                            \
    __builtin_amdgcn_s_setprio(0);                                                 \
  }

#define GITER(cur, st)                                                             \
  {                                                                                \
    asm volatile("s_barrier" ::: "memory");                                        \
    { const int s1 = (st) + 1 < GSTEPS ? (st) + 1 : GSTEPS - 1;                    \
      GSTAGE((cur) ^ 1, s1); }                                                     \
    asm volatile("s_waitcnt vmcnt(8)" ::: "memory");                               \
    asm volatile("s_barrier" ::: "memory");                                        \
    GCOMP(cur);                                                                    \
  }

  GSTAGE(0, 0);
#pragma unroll
  for (int s = 0; s < GSTEPS; ++s) GITER(s & 1, s);
#undef GITER
#undef GCOMP
#undef GSTAGE

  // epilogue: C/D layout col = lane&15, row = (lane>>4)*4 + reg
#pragma unroll
  for (int ni = 0; ni < 4; ++ni) {
    const int col = n0 + wc*64 + ni*16 + r;
    const float bv = bias[col];                       // MODE 1: permuted bias
    if (MODE == 0) {
#pragma unroll
      for (int mi = 0; mi < 4; ++mi)
#pragma unroll
        for (int q = 0; q < 4; ++q) {
          const int rowg = m0 + wr*64 + mi*16 + g*4 + q;
          Cf[(size_t)rowg * N + col] = acc[mi][ni][q] + bv;
        }
    } else {
      const int which = col / 768;
      const int h_ = (col - which * 768) >> 6;
      const int d_ = col & 63;
      if (which == 2) {
#pragma unroll
        for (int mi = 0; mi < 4; ++mi) {
          const int nn0 = m0 + wr*64 + mi*16 + g*4;   // multiple of 4
          const int bb = nn0 >> 11, nl = nn0 & 2047;
          const int np0 = (nl & ~12) | ((nl & 4) << 1) | ((nl & 8) >> 1);
          uint2 u;
          u.x = pk2bf(acc[mi][ni][0] + bv, acc[mi][ni][1] + bv);
          u.y = pk2bf(acc[mi][ni][2] + bv, acc[mi][ni][3] + bv);
          *reinterpret_cast<uint2*>(Vt + ((size_t)(bb*HEADS + h_)*DH + d_)*SEQ + np0) = u;
        }
      } else {
        ushort_t* dst = (which == 0) ? Qd : Kd;
        const float sc = (which == 0) ? LOG2E : 1.0f;
#pragma unroll
        for (int mi = 0; mi < 4; ++mi)
#pragma unroll
          for (int q = 0; q < 4; ++q) {
            const int rowg = m0 + wr*64 + mi*16 + g*4 + q;
            const int bb = rowg >> 11, nn = rowg & 2047;
            dst[((size_t)(bb*HEADS + h_)*SEQ + nn)*DH + d_] =
                f2bf((acc[mi][ni][q] + bv) * sc);
          }
      }
    }
  }
}

// ---------------- flash attention: 3-buffer LDS pipeline, counted vmcnt ----------------
// (r9 version verbatim -- best measured at ~70.7us across 4 independent rounds)
#define NTIL 32

__global__ __launch_bounds__(256, 3) void attn_fwd(
    const ushort_t* __restrict__ Qd, const ushort_t* __restrict__ Kd,
    const ushort_t* __restrict__ Vt, ushort_t* __restrict__ Oa)
{
  __shared__ alignas(16) char L[3][16384];   // per buf: K 8KB (seg*1024+key*16) | V 8KB
  char* Lc = &L[0][0];

  const int t = threadIdx.x;
  const int w = t >> 6, l = t & 63;
  const int c31 = l & 31, hi = l >> 5;
  const int blk = blockIdx.x;
  const int logical = (blk & 7) * 96 + (blk >> 3);   // XCD-chunked: 6 bh per XCD
  const int bh = logical >> 4;
  const int qt = logical & 15;
  const int q0 = qt * 128 + w * 32;
  const int b = bh / HEADS, h = bh - b * HEADS;

  const ushort_t* Qp = Qd + (size_t)bh * SEQ * DH;
  const ushort_t* Kp = Kd + (size_t)bh * SEQ * DH;
  const ushort_t* Vp = Vt + (size_t)bh * DH * SEQ;

  s16x8 qf[4];
  {
    const ushort_t* qp = Qp + (size_t)(q0 + c31) * DH + hi * 8;
#pragma unroll
    for (int c = 0; c < 4; ++c) qf[c] = *(const s16x8*)(qp + c * 16);
  }

  f32x16 oacc0 = {}, oacc1 = {};   // O^T d 0..31 / 32..63; col q = l&31
  float ps0 = 0.f, ps1 = 0.f, ps2 = 0.f, ps3 = 0.f;

  const int ldsb = hi * 1024 + c31 * 16;             // per-lane ds_read base (byte)
  const ushort_t* ksrc0 = Kp + (size_t)l * DH + w * 16;   // + tile*4096
  const ushort_t* vsrc0 = Vp + (size_t)l * SEQ + w * 16;  // + tile*64
  char* kdst0 = Lc + w * 2048 + l * 16;                   // + buf*16384

#define STAGE(bufc, tile_)                                                         \
  {                                                                                \
    const int tl = (tile_);                                                        \
    const ushort_t* ks = ksrc0 + (size_t)tl * (64 * DH);                           \
    const ushort_t* vs = vsrc0 + tl * 64;                                          \
    char* kd = kdst0 + (bufc) * 16384;                                             \
    gload_lds16(ks,     kd);                                                       \
    gload_lds16(ks + 8, kd + 1024);                                                \
    gload_lds16(vs,     kd + 8192);                                                \
    gload_lds16(vs + 8, kd + 9216);                                                \
  }

#define KGROUP(bufc, kg)                                                           \
  {                                                                                \
    const char* base = Lc + (bufc) * 16384 + ldsb;                                 \
    s16x8 kf0 = *(const s16x8*)(base + ((kg)*512 + 0*2048));                       \
    s16x8 kf1 = *(const s16x8*)(base + ((kg)*512 + 1*2048));                       \
    s16x8 kf2 = *(const s16x8*)(base + ((kg)*512 + 2*2048));                       \
    s16x8 kf3 = *(const s16x8*)(base + ((kg)*512 + 3*2048));                       \
    s16x8 va00 = *(const s16x8*)(base + (8192 + (kg)*4096 + 0*2048 + 0*512));      \
    s16x8 va01 = *(const s16x8*)(base + (8192 + (kg)*4096 + 1*2048 + 0*512));      \
    s16x8 va10 = *(const s16x8*)(base + (8192 + (kg)*4096 + 0*2048 + 1*512));      \
    s16x8 va11 = *(const s16x8*)(base + (8192 + (kg)*4096 + 1*2048 + 1*512));      \
    __builtin_amdgcn_s_setprio(1);                                                 \
    f32x16 s = {};                                                                 \
    s = __builtin_amdgcn_mfma_f32_32x32x16_bf16(kf0, qf[0], s, 0, 0, 0);           \
    s = __builtin_amdgcn_mfma_f32_32x32x16_bf16(kf1, qf[1], s, 0, 0, 0);           \
    s = __builtin_amdgcn_mfma_f32_32x32x16_bf16(kf2, qf[2], s, 0, 0, 0);           \
    s = __builtin_amdgcn_mfma_f32_32x32x16_bf16(kf3, qf[3], s, 0, 0, 0);           \
    __builtin_amdgcn_s_setprio(0);                                                 \
    float pe[16];                                                                  \
    _Pragma("unroll")                                                              \
    for (int r2 = 0; r2 < 16; ++r2) pe[r2] = __builtin_amdgcn_exp2f(s[r2]);        \
    ps0 += (pe[0]  + pe[1])  + (pe[2]  + pe[3]);                                   \
    ps1 += (pe[4]  + pe[5])  + (pe[6]  + pe[7]);                                   \
    ps2 += (pe[8]  + pe[9])  + (pe[10] + pe[11]);                                  \
    ps3 += (pe[12] + pe[13]) + (pe[14] + pe[15]);                                  \
    u32x4 f0u = { cvtpk(pe[0],  pe[1]),  cvtpk(pe[2],  pe[3]),                     \
                  cvtpk(pe[4],  pe[5]),  cvtpk(pe[6],  pe[7]) };                   \
    u32x4 f1u = { cvtpk(pe[8],  pe[9]),  cvtpk(pe[10], pe[11]),                    \
                  cvtpk(pe[12], pe[13]), cvtpk(pe[14], pe[15]) };                  \
    const s16x8 pf0 = __builtin_bit_cast(s16x8, f0u);                              \
    const s16x8 pf1 = __builtin_bit_cast(s16x8, f1u);                              \
    __builtin_amdgcn_s_setprio(1);                                                 \
    oacc0 = __builtin_amdgcn_mfma_f32_32x32x16_bf16(va00, pf0, oacc0, 0, 0, 0);    \
    oacc0 = __builtin_amdgcn_mfma_f32_32x32x16_bf16(va01, pf1, oacc0, 0, 0, 0);    \
    oacc1 = __builtin_amdgcn_mfma_f32_32x32x16_bf16(va10, pf0, oacc1, 0, 0, 0);    \
    oacc1 = __builtin_amdgcn_mfma_f32_32x32x16_bf16(va11, pf1, oacc1, 0, 0, 0);    \
    __builtin_amdgcn_s_setprio(0);                                                 \
  }

#define ITER(bufcur, bufn2, tt)                                                    \
  {                                                                                \
    asm volatile("s_barrier" ::: "memory");                                        \
    const int nt2 = (tt) + 2 < NTIL ? (tt) + 2 : NTIL - 1;                         \
    STAGE(bufn2, nt2);                                                             \
    asm volatile("s_waitcnt vmcnt(8)" ::: "memory");                               \
    asm volatile("s_barrier" ::: "memory");                                        \
    KGROUP(bufcur, 0);                                                             \
    KGROUP(bufcur, 1);                                                             \
  }

  STAGE(0, 0);
  STAGE(1, 1);
  for (int tt = 0; tt < NTIL - 2; tt += 3) {
    ITER(0, 2, tt);
    ITER(1, 0, tt + 1);
    ITER(2, 1, tt + 2);
  }
  ITER(0, 2, 30);
  ITER(1, 0, 31);
#undef ITER
#undef KGROUP
#undef STAGE

  const float psum = (ps0 + ps1) + (ps2 + ps3);
  const float lt = psum + __shfl_xor(psum, 32);
  const float scale = 0.036084391824351615f / lt;   // (1/sqrt(768)) / l

  ushort_t* op = Oa + ((size_t)(b * SEQ + q0 + c31)) * EMB + h * DH;
#pragma unroll
  for (int f = 0; f < 2; ++f) {
    const f32x16& o = f ? oacc1 : oacc0;
#pragma unroll
    for (int rq = 0; rq < 4; ++rq) {
      const int dbase = f * 32 + 8 * rq + 4 * hi;    // d = dbase + (reg&3)
      uint2 u;
      u.x = pk2bf(o[rq*4+0] * scale, o[rq*4+1] * scale);
      u.y = pk2bf(o[rq*4+2] * scale, o[rq*4+3] * scale);
      *reinterpret_cast<uint2*>(op + dbase) = u;
    }
  }
}

// ---------------- host launch ----------------
extern "C" void kernel_launch(void* const* d_in, const int* in_sizes, int n_in,
                              void* d_out, int out_size, void* d_ws, size_t ws_size,
                              hipStream_t stream) {
  const float* x      = (const float*)d_in[0];
  const float* qkv_w  = (const float*)d_in[1];
  const float* qkv_b  = (const float*)d_in[2];
  const float* proj_w = (const float*)d_in[3];
  const float* proj_b = (const float*)d_in[4];
  float* out = (float*)d_out;

  ushort_t* xb    = (ushort_t*)d_ws;
  ushort_t* wqkv  = xb    + (size_t)MTOK*EMB;
  ushort_t* wproj = wqkv  + (size_t)NQKV*EMB;
  ushort_t* Qd    = wproj + (size_t)EMB*EMB;
  ushort_t* Kd    = Qd    + (size_t)MTOK*EMB;
  ushort_t* Vt    = Kd    + (size_t)MTOK*EMB;
  ushort_t* Oa    = Vt    + (size_t)MTOK*EMB;
  float*    biasp = (float*)(Oa + (size_t)MTOK*EMB);   // 2304 fp32 permuted bias

  cvt_all<<<(N4X + N4W + N4P) / 256, 256, 0, stream>>>(
      x, qkv_w, qkv_b, proj_w, xb, wqkv, biasp, wproj);

  gemm_bt<1><<<dim3(NQKV/TN, MTOK/TM), 256, 0, stream>>>(
      xb, wqkv, biasp, nullptr, Qd, Kd, Vt, MTOK, NQKV, EMB);

  attn_fwd<<<768, 256, 0, stream>>>(Qd, Kd, Vt, Oa);

  gemm_bt<0><<<dim3(EMB/TN, MTOK/TM), 256, 0, stream>>>(
      Oa, wproj, proj_b, out, nullptr, nullptr, nullptr, MTOK, EMB, EMB);
}